// Round 18
// baseline (144.373 us; speedup 1.0000x reference)
//
#include <hip/hip_runtime.h>

#define N_NODES 100000
#define N_EDGES 1600000
#define IN_C 32
#define HID_C 64
#define OUT_C 32

#define EPB 4096                                 // edges per place block
#define NBLK ((N_EDGES + EPB - 1) / EPB)         // 391
#define BSH 8                                    // 256 nodes per bucket
#define BKN (1 << BSH)
#define NB ((N_NODES + BKN - 1) / BKN)           // 391
#define REG 4608                                 // fixed slots per bucket
#define NSLOT (NB * BKN)                         // 100096 nsort entries

typedef __attribute__((ext_vector_type(8))) short bf16x8;
typedef __attribute__((ext_vector_type(8))) unsigned short u16x8;
typedef __attribute__((ext_vector_type(4))) float f32x4;

__device__ __forceinline__ unsigned short f2bf(float f) {
    unsigned u = __float_as_uint(f);
    return (unsigned short)((u + 0x7fffu + ((u >> 16) & 1u)) >> 16);
}
__device__ __forceinline__ float bf2f(unsigned short h) {
    return __uint_as_float((unsigned)h << 16);
}

// ---- weights cast + zero bucket counters --------------------------------
__global__ void cast_w_kernel(const float* __restrict__ w1l,
                              const float* __restrict__ w1r,
                              const float* __restrict__ w2l,
                              const float* __restrict__ w2r,
                              ushort* __restrict__ wb, int* __restrict__ bcnt) {
    for (int i = threadIdx.x; i < NB; i += 256) bcnt[i] = 0;
    for (int i = threadIdx.x; i < 8192; i += 256) {
        float v;
        if (i < 2048) v = w1l[i];
        else if (i < 4096) v = w1r[i - 2048];
        else if (i < 6144) v = w2l[i - 4096];
        else v = w2r[i - 6144];
        wb[i] = f2bf(v);
    }
}

// ---- place: LDS hist -> global range reservation -> write packed pairs --
__global__ __launch_bounds__(256) void place_kernel(
    const int* __restrict__ src, const int* __restrict__ dst,
    const float* __restrict__ x, ushort* __restrict__ xbA,
    ushort* __restrict__ xbB, int* __restrict__ bcnt,
    unsigned* __restrict__ tmp) {
    for (int ci = blockIdx.x * 256 + threadIdx.x; ci < N_NODES * IN_C / 8;
         ci += NBLK * 256) {
        int n = ci >> 2;
        int oc = ci & 3;
        const float4* p = (const float4*)&x[(size_t)ci * 8];
        float4 a = p[0], b = p[1];
        u16x8 o;
        o[0] = f2bf(a.x); o[1] = f2bf(a.y); o[2] = f2bf(a.z); o[3] = f2bf(a.w);
        o[4] = f2bf(b.x); o[5] = f2bf(b.y); o[6] = f2bf(b.z); o[7] = f2bf(b.w);
        ushort* dstp = (oc < 2) ? xbA : xbB;
        *(u16x8*)&dstp[(size_t)n * 16 + (oc & 1) * 8] = o;
    }

    __shared__ int lh[NB];
    __shared__ int cur[NB];
    for (int i = threadIdx.x; i < NB; i += 256) lh[i] = 0;
    __syncthreads();

    int base = blockIdx.x * EPB;
    int se[16], de[16];
#pragma unroll
    for (int j = 0; j < 16; ++j) {
        int e = base + j * 256 + threadIdx.x;
        bool v = e < N_EDGES;
        se[j] = v ? src[e] : -1;
        de[j] = v ? dst[e] : 0;
        if (v) atomicAdd(&lh[de[j] >> BSH], 1);
    }
    __syncthreads();
    for (int i = threadIdx.x; i < NB; i += 256)
        cur[i] = i * REG + atomicAdd(&bcnt[i], lh[i]);
    __syncthreads();
#pragma unroll
    for (int j = 0; j < 16; ++j) {
        if (se[j] >= 0) {
            int slot = atomicAdd(&cur[de[j] >> BSH], 1);
            tmp[slot] = ((unsigned)se[j] << 8) | (unsigned)(de[j] & (BKN - 1));
        }
    }
}

// ---- count_place: per-bucket perm + degree-sorted node list -------------
// Emits nsort[b*256+rank] = { rowptr | cnt<<21 , node }, rank ordered by
// degree within the bucket -> gather waves (32 consecutive ranks) have
// near-uniform per-lane loop counts (kills the 1.8x max-of-32 divergence).
__global__ __launch_bounds__(512) void count_place_kernel(
    const unsigned* __restrict__ tmp, const int* __restrict__ bcnt,
    uint2* __restrict__ nsort, int* __restrict__ perm) {
    __shared__ int lcnt[BKN];
    __shared__ int sscan[BKN];
    __shared__ int cur[BKN];
    __shared__ int dbin[64];
    int b = blockIdx.x;
    int tid = threadIdx.x;
    int start = b * REG;
    int end = start + bcnt[b];

    unsigned pv[9];
    int npv = 0;
    for (int i = start + tid; i < end; i += 512) pv[npv++] = tmp[i];

    if (tid < BKN) lcnt[tid] = 0;
    if (tid < 64) dbin[tid] = 0;
    __syncthreads();
    for (int k = 0; k < npv; ++k)
        atomicAdd(&lcnt[pv[k] & (BKN - 1)], 1);
    __syncthreads();
    int myc = 0, mybin = 0;
    if (tid < BKN) {
        myc = lcnt[tid];
        mybin = myc < 63 ? myc : 63;
        sscan[tid] = myc;
        atomicAdd(&dbin[mybin], 1);
    }
    __syncthreads();
    for (int o = 1; o < BKN; o <<= 1) {
        int v = 0;
        if (tid < BKN && tid >= o) v = sscan[tid - o];
        __syncthreads();
        if (tid < BKN) sscan[tid] += v;
        __syncthreads();
    }
    if (tid == 0) {                 // tiny 64-bin exclusive scan
        int a = 0;
#pragma unroll
        for (int i = 0; i < 64; ++i) { int c = dbin[i]; dbin[i] = a; a += c; }
    }
    int excl = 0;
    if (tid < BKN) {
        excl = sscan[tid] - myc + start;
        cur[tid] = excl;
    }
    __syncthreads();
    if (tid < BKN) {
        int rank = atomicAdd(&dbin[mybin], 1);
        int n = (b << BSH) + tid;
        nsort[(b << BSH) + rank] =
            make_uint2((unsigned)excl | ((unsigned)myc << 21), (unsigned)n);
    }
    __syncthreads();
    for (int k = 0; k < npv; ++k) {
        int slot = atomicAdd(&cur[pv[k] & (BKN - 1)], 1);
        perm[slot] = (int)(pv[k] >> 8);
    }
}

// 784 blocks per half, 128 node-slots/block; grid = 1568 (multiple of 8).
// XCD partition: blockIdx%8 in {0..3} -> half A, {4..7} -> half B, so each
// XCD's 4MB L2 holds ONE 3.2MB half-table while both halves run at full TLP.
#define GSG8 784

// ---- serial-per-lane gather-mean, degree-sorted, XCD-partitioned --------
__global__ __launch_bounds__(256) void gather_mean_kernel(
    const ushort* __restrict__ xbA, const ushort* __restrict__ xbB,
    const uint2* __restrict__ nsort, const int* __restrict__ perm,
    ushort* __restrict__ mbA, ushort* __restrict__ mbB) {
    int g = blockIdx.x;
    int xcd = g & 7;
    int half = xcd >> 2;
    int sub = ((g >> 3) << 2) | (xcd & 3);       // 0..783 per half
    const ushort* xh = half ? xbB : xbA;
    ushort* mh = half ? mbB : mbA;
    int lane = threadIdx.x & 63;
    int wid = threadIdx.x >> 6;
    int slot = (sub * 4 + wid) * 32 + (lane >> 1);
    int q = lane & 1;
    if (slot >= NSLOT) return;
    uint2 ns = nsort[slot];
    int st = (int)(ns.x & 0x1FFFFFu);
    int cn = (int)(ns.x >> 21);
    int n = (int)ns.y;

    float acc[8] = {0, 0, 0, 0, 0, 0, 0, 0};
    int i = 0;
    for (; i + 4 <= cn; i += 4) {
        int p0 = perm[st + i + 0];
        int p1 = perm[st + i + 1];
        int p2 = perm[st + i + 2];
        int p3 = perm[st + i + 3];
        u16x8 v0 = *(const u16x8*)&xh[(size_t)p0 * 16 + q * 8];
        u16x8 v1 = *(const u16x8*)&xh[(size_t)p1 * 16 + q * 8];
        u16x8 v2 = *(const u16x8*)&xh[(size_t)p2 * 16 + q * 8];
        u16x8 v3 = *(const u16x8*)&xh[(size_t)p3 * 16 + q * 8];
#pragma unroll
        for (int j = 0; j < 8; ++j)
            acc[j] += (bf2f(v0[j]) + bf2f(v1[j])) + (bf2f(v2[j]) + bf2f(v3[j]));
    }
    for (; i < cn; ++i) {
        int p = perm[st + i];
        u16x8 v = *(const u16x8*)&xh[(size_t)p * 16 + q * 8];
#pragma unroll
        for (int j = 0; j < 8; ++j) acc[j] += bf2f(v[j]);
    }

    if (n < N_NODES) {
        float inv = 1.0f / fmaxf((float)cn, 1.0f);
        u16x8 o;
#pragma unroll
        for (int j = 0; j < 8; ++j) o[j] = f2bf(acc[j] * inv);
        *(u16x8*)&mh[(size_t)n * 16 + q * 8] = o;
    }
}

// ---- serial-per-lane gather-final, degree-sorted, XCD-partitioned -------
__global__ __launch_bounds__(256) void gather_final_kernel(
    const ushort* __restrict__ tbA, const ushort* __restrict__ tbB,
    const uint2* __restrict__ nsort, const int* __restrict__ perm,
    const float* __restrict__ rA, const float* __restrict__ rB,
    float* __restrict__ out) {
    int g = blockIdx.x;
    int xcd = g & 7;
    int half = xcd >> 2;
    int sub = ((g >> 3) << 2) | (xcd & 3);
    const ushort* th = half ? tbB : tbA;
    const float* rh = half ? rB : rA;
    int lane = threadIdx.x & 63;
    int wid = threadIdx.x >> 6;
    int slot = (sub * 4 + wid) * 32 + (lane >> 1);
    int q = lane & 1;
    if (slot >= NSLOT) return;
    uint2 ns = nsort[slot];
    int st = (int)(ns.x & 0x1FFFFFu);
    int cn = (int)(ns.x >> 21);
    int n = (int)ns.y;

    float acc[8] = {0, 0, 0, 0, 0, 0, 0, 0};
    int i = 0;
    for (; i + 4 <= cn; i += 4) {
        int p0 = perm[st + i + 0];
        int p1 = perm[st + i + 1];
        int p2 = perm[st + i + 2];
        int p3 = perm[st + i + 3];
        u16x8 v0 = *(const u16x8*)&th[(size_t)p0 * 16 + q * 8];
        u16x8 v1 = *(const u16x8*)&th[(size_t)p1 * 16 + q * 8];
        u16x8 v2 = *(const u16x8*)&th[(size_t)p2 * 16 + q * 8];
        u16x8 v3 = *(const u16x8*)&th[(size_t)p3 * 16 + q * 8];
#pragma unroll
        for (int j = 0; j < 8; ++j)
            acc[j] += (bf2f(v0[j]) + bf2f(v1[j])) + (bf2f(v2[j]) + bf2f(v3[j]));
    }
    for (; i < cn; ++i) {
        int p = perm[st + i];
        u16x8 v = *(const u16x8*)&th[(size_t)p * 16 + q * 8];
#pragma unroll
        for (int j = 0; j < 8; ++j) acc[j] += bf2f(v[j]);
    }

    if (n < N_NODES) {
        float inv = 1.0f / fmaxf((float)cn, 1.0f);
        const float4* rp = (const float4*)&rh[(size_t)n * 16 + q * 8];
        float4 r0 = rp[0], r1 = rp[1];
        float4* op = (float4*)&out[(size_t)n * 32 + half * 16 + q * 8];
        op[0] = make_float4(acc[0] * inv + r0.x, acc[1] * inv + r0.y,
                            acc[2] * inv + r0.z, acc[3] * inv + r0.w);
        op[1] = make_float4(acc[4] * inv + r1.x, acc[5] * inv + r1.y,
                            acc[6] * inv + r1.z, acc[7] * inv + r1.w);
    }
}

// ---- MFMA transform: reads/writes split half-tables ---------------------
__global__ __launch_bounds__(256) void transform_mfma_kernel(
    const ushort* __restrict__ xbA, const ushort* __restrict__ xbB,
    const ushort* __restrict__ mbA, const ushort* __restrict__ mbB,
    const ushort* __restrict__ wb, const float* __restrict__ b1,
    const float* __restrict__ b2, ushort* __restrict__ tbA,
    ushort* __restrict__ tbB, float* __restrict__ rA,
    float* __restrict__ rB) {
    __shared__ ushort hlds[4][16 * 72];
    int lane = threadIdx.x & 63;
    int wid = threadIdx.x >> 6;
    int l15 = lane & 15, lhi = lane >> 4;

    const ushort* w1l = wb;
    const ushort* w1r = wb + 2048;
    const ushort* w2l = wb + 4096;
    const ushort* w2r = wb + 6144;

    bf16x8 B1l[4], B1r[4];
#pragma unroll
    for (int jt = 0; jt < 4; ++jt) {
        B1l[jt] = *(const bf16x8*)&w1l[(jt * 16 + l15) * 32 + 8 * lhi];
        B1r[jt] = *(const bf16x8*)&w1r[(jt * 16 + l15) * 32 + 8 * lhi];
    }
    bf16x8 B2l[2][2], B2r[2][2];
#pragma unroll
    for (int ct = 0; ct < 2; ++ct)
#pragma unroll
        for (int kc = 0; kc < 2; ++kc) {
            B2l[ct][kc] = *(const bf16x8*)&w2l[(ct * 16 + l15) * 64 + kc * 32 + 8 * lhi];
            B2r[ct][kc] = *(const bf16x8*)&w2r[(ct * 16 + l15) * 64 + kc * 32 + 8 * lhi];
        }
    float bias1[4];
#pragma unroll
    for (int jt = 0; jt < 4; ++jt) bias1[jt] = b1[jt * 16 + l15];
    float bias2[2] = { b2[l15], b2[16 + l15] };

    ushort* hl = hlds[wid];

#pragma unroll
    for (int chunk = 0; chunk < 2; ++chunk) {
        int n0 = blockIdx.x * 128 + wid * 32 + chunk * 16;
        int nrow = n0 + l15;
        bf16x8 Am = {}, Ax = {};
        if (nrow < N_NODES) {
            const ushort* ms = (lhi < 2) ? mbA : mbB;
            const ushort* xs = (lhi < 2) ? xbA : xbB;
            Am = *(const bf16x8*)&ms[(size_t)nrow * 16 + 8 * (lhi & 1)];
            Ax = *(const bf16x8*)&xs[(size_t)nrow * 16 + 8 * (lhi & 1)];
        }
#pragma unroll
        for (int jt = 0; jt < 4; ++jt) {
            f32x4 acc = {};
            acc = __builtin_amdgcn_mfma_f32_16x16x32_bf16(Am, B1l[jt], acc, 0, 0, 0);
            acc = __builtin_amdgcn_mfma_f32_16x16x32_bf16(Ax, B1r[jt], acc, 0, 0, 0);
#pragma unroll
            for (int reg = 0; reg < 4; ++reg) {
                float h = fmaxf(acc[reg] + bias1[jt], 0.0f);
                hl[(lhi * 4 + reg) * 72 + jt * 16 + l15] = f2bf(h);
            }
        }
        bf16x8 Ah0 = *(const bf16x8*)&hl[l15 * 72 + 8 * lhi];
        bf16x8 Ah1 = *(const bf16x8*)&hl[l15 * 72 + 32 + 8 * lhi];
#pragma unroll
        for (int ct = 0; ct < 2; ++ct) {
            f32x4 acc = {};
            acc = __builtin_amdgcn_mfma_f32_16x16x32_bf16(Ah0, B2l[ct][0], acc, 0, 0, 0);
            acc = __builtin_amdgcn_mfma_f32_16x16x32_bf16(Ah1, B2l[ct][1], acc, 0, 0, 0);
            ushort* tdst = ct ? tbB : tbA;
#pragma unroll
            for (int reg = 0; reg < 4; ++reg) {
                int nr = n0 + lhi * 4 + reg;
                if (nr < N_NODES)
                    tdst[(size_t)nr * 16 + l15] = f2bf(acc[reg]);
            }
        }
#pragma unroll
        for (int ct = 0; ct < 2; ++ct) {
            f32x4 acc = {};
            acc = __builtin_amdgcn_mfma_f32_16x16x32_bf16(Ah0, B2r[ct][0], acc, 0, 0, 0);
            acc = __builtin_amdgcn_mfma_f32_16x16x32_bf16(Ah1, B2r[ct][1], acc, 0, 0, 0);
            float* rdst = ct ? rB : rA;
#pragma unroll
            for (int reg = 0; reg < 4; ++reg) {
                int nr = n0 + lhi * 4 + reg;
                if (nr < N_NODES)
                    rdst[(size_t)nr * 16 + l15] = acc[reg] + bias2[ct];
            }
        }
    }
}

// ---- launch -------------------------------------------------------------

extern "C" void kernel_launch(void* const* d_in, const int* in_sizes, int n_in,
                              void* d_out, int out_size, void* d_ws, size_t ws_size,
                              hipStream_t stream) {
    const float* x   = (const float*)d_in[0];
    const float* W1l = (const float*)d_in[1];
    const float* W1r = (const float*)d_in[2];
    const float* b1  = (const float*)d_in[3];
    const float* W2l = (const float*)d_in[4];
    const float* W2r = (const float*)d_in[5];
    const float* b2  = (const float*)d_in[6];
    const int*   ei  = (const int*)d_in[7];   // [2, N_EDGES]
    const int* src = ei;
    const int* dst = ei + N_EDGES;

    char* ws = (char*)d_ws;
    int*      bcnt   = (int*)ws;             ws += (size_t)(NB + 8) * 4;
    uint2*    nsort  = (uint2*)ws;           ws += (size_t)NSLOT * 8;       // 800 KB
    int*      perm   = (int*)ws;             ws += (size_t)NB * REG * 4;    // 7.2 MB
    unsigned* tmp    = (unsigned*)ws;        ws += (size_t)NB * REG * 4;    // 7.2 MB
    // mbA/mbB (3.2MB each) alias tmp (7.2MB): tmp dead after count_place.
    ushort*   mbA    = (ushort*)tmp;
    ushort*   mbB    = mbA + (size_t)N_NODES * 16;
    ushort*   xbA    = (ushort*)ws;          ws += (size_t)N_NODES * 16 * 2;
    ushort*   xbB    = (ushort*)ws;          ws += (size_t)N_NODES * 16 * 2;
    ushort*   wb     = (ushort*)ws;          ws += (size_t)8192 * 2;
    ushort*   tbA    = (ushort*)ws;          ws += (size_t)N_NODES * 16 * 2;
    ushort*   tbB    = (ushort*)ws;          ws += (size_t)N_NODES * 16 * 2;
    float*    rA     = (float*)ws;           ws += (size_t)N_NODES * 16 * 4;
    float*    rB     = (float*)ws;           ws += (size_t)N_NODES * 16 * 4;

    dim3 blk(256);

    cast_w_kernel<<<1, blk, 0, stream>>>(W1l, W1r, W2l, W2r, wb, bcnt);
    place_kernel<<<NBLK, blk, 0, stream>>>(src, dst, x, xbA, xbB, bcnt, tmp);
    count_place_kernel<<<NB, dim3(512), 0, stream>>>(tmp, bcnt, nsort, perm);

    gather_mean_kernel<<<2 * GSG8, blk, 0, stream>>>(xbA, xbB, nsort, perm,
                                                     mbA, mbB);
    transform_mfma_kernel<<<(N_NODES + 127) / 128, blk, 0, stream>>>(
        xbA, xbB, mbA, mbB, wb, b1, b2, tbA, tbB, rA, rB);
    gather_final_kernel<<<2 * GSG8, blk, 0, stream>>>(tbA, tbB, nsort, perm,
                                                      rA, rB, (float*)d_out);
}

// Round 19
// 136.507 us; speedup vs baseline: 1.0576x; 1.0576x over previous
//
#include <hip/hip_runtime.h>

#define N_NODES 100000
#define N_EDGES 1600000
#define IN_C 32
#define HID_C 64
#define OUT_C 32

#define EPB 4096                                 // edges per place block
#define NBLK ((N_EDGES + EPB - 1) / EPB)         // 391
#define BSH 8                                    // 256 nodes per bucket
#define BKN (1 << BSH)
#define NB ((N_NODES + BKN - 1) / BKN)           // 391
#define REG 4608                                 // fixed slots per bucket

typedef __attribute__((ext_vector_type(8))) short bf16x8;
typedef __attribute__((ext_vector_type(8))) unsigned short u16x8;
typedef __attribute__((ext_vector_type(4))) float f32x4;

__device__ __forceinline__ unsigned short f2bf(float f) {
    unsigned u = __float_as_uint(f);
    return (unsigned short)((u + 0x7fffu + ((u >> 16) & 1u)) >> 16);
}
__device__ __forceinline__ float bf2f(unsigned short h) {
    return __uint_as_float((unsigned)h << 16);
}
// load 8 consecutive f32 and pack to bf16x8 (for weight fragments)
__device__ __forceinline__ bf16x8 pk8(const float* p) {
    const float4* q = (const float4*)p;
    float4 a = q[0], b = q[1];
    bf16x8 r;
    r[0] = (short)f2bf(a.x); r[1] = (short)f2bf(a.y);
    r[2] = (short)f2bf(a.z); r[3] = (short)f2bf(a.w);
    r[4] = (short)f2bf(b.x); r[5] = (short)f2bf(b.y);
    r[6] = (short)f2bf(b.z); r[7] = (short)f2bf(b.w);
    return r;
}

// ---- place: LDS hist -> global range reservation -> write packed pairs --
// Edges kept in registers (one read of src/dst). Fixed per-bucket regions
// (bucket b owns tmp[b*REG .. b*REG+REG)). Fuses the x -> bf16 split-cast.
__global__ __launch_bounds__(256) void place_kernel(
    const int* __restrict__ src, const int* __restrict__ dst,
    const float* __restrict__ x, ushort* __restrict__ xbA,
    ushort* __restrict__ xbB, int* __restrict__ bcnt,
    unsigned* __restrict__ tmp) {
    for (int ci = blockIdx.x * 256 + threadIdx.x; ci < N_NODES * IN_C / 8;
         ci += NBLK * 256) {
        int n = ci >> 2;
        int oc = ci & 3;
        const float4* p = (const float4*)&x[(size_t)ci * 8];
        float4 a = p[0], b = p[1];
        u16x8 o;
        o[0] = f2bf(a.x); o[1] = f2bf(a.y); o[2] = f2bf(a.z); o[3] = f2bf(a.w);
        o[4] = f2bf(b.x); o[5] = f2bf(b.y); o[6] = f2bf(b.z); o[7] = f2bf(b.w);
        ushort* dstp = (oc < 2) ? xbA : xbB;
        *(u16x8*)&dstp[(size_t)n * 16 + (oc & 1) * 8] = o;
    }

    __shared__ int lh[NB];
    __shared__ int cur[NB];
    for (int i = threadIdx.x; i < NB; i += 256) lh[i] = 0;
    __syncthreads();

    int base = blockIdx.x * EPB;
    int se[16], de[16];
#pragma unroll
    for (int j = 0; j < 16; ++j) {
        int e = base + j * 256 + threadIdx.x;
        bool v = e < N_EDGES;
        se[j] = v ? src[e] : -1;
        de[j] = v ? dst[e] : 0;
        if (v) atomicAdd(&lh[de[j] >> BSH], 1);
    }
    __syncthreads();
    for (int i = threadIdx.x; i < NB; i += 256)
        cur[i] = i * REG + atomicAdd(&bcnt[i], lh[i]);
    __syncthreads();
#pragma unroll
    for (int j = 0; j < 16; ++j) {
        if (se[j] >= 0) {
            int slot = atomicAdd(&cur[de[j] >> BSH], 1);
            tmp[slot] = ((unsigned)se[j] << 8) | (unsigned)(de[j] & (BKN - 1));
        }
    }
}

// ---- count_place: per-bucket counts + rowptr + perm (one tmp read) ------
__global__ __launch_bounds__(512) void count_place_kernel(
    const unsigned* __restrict__ tmp, const int* __restrict__ bcnt,
    int* __restrict__ counts, int* __restrict__ rowptr,
    int* __restrict__ perm) {
    __shared__ int lcnt[BKN];
    __shared__ int sscan[BKN];
    __shared__ int cur[BKN];
    int b = blockIdx.x;
    int tid = threadIdx.x;
    int start = b * REG;
    int end = start + bcnt[b];

    unsigned pv[9];
    int npv = 0;
    for (int i = start + tid; i < end; i += 512) pv[npv++] = tmp[i];

    if (tid < BKN) lcnt[tid] = 0;
    __syncthreads();
    for (int k = 0; k < npv; ++k)
        atomicAdd(&lcnt[pv[k] & (BKN - 1)], 1);
    __syncthreads();
    if (tid < BKN) sscan[tid] = lcnt[tid];
    __syncthreads();
    for (int o = 1; o < BKN; o <<= 1) {
        int v = 0;
        if (tid < BKN && tid >= o) v = sscan[tid - o];
        __syncthreads();
        if (tid < BKN) sscan[tid] += v;
        __syncthreads();
    }
    if (tid < BKN) {
        int excl = sscan[tid] - lcnt[tid] + start;
        cur[tid] = excl;
        int n = (b << BSH) + tid;
        if (n < N_NODES) { rowptr[n] = excl; counts[n] = lcnt[tid]; }
    }
    __syncthreads();
    for (int k = 0; k < npv; ++k) {
        int slot = atomicAdd(&cur[pv[k] & (BKN - 1)], 1);
        perm[slot] = (int)(pv[k] >> 8);
    }
}

// 784 blocks per half, 128 nodes/block; grid = 1568 (multiple of 8).
// XCD partition: blockIdx%8 in {0..3} -> half A, {4..7} -> half B, so each
// XCD's 4MB L2 holds ONE 3.2MB half-table while both halves run at full TLP.
#define GSG8 784

// ---- serial-per-lane gather-mean, XCD-partitioned halves ----------------
__global__ __launch_bounds__(256) void gather_mean_kernel(
    const ushort* __restrict__ xbA, const ushort* __restrict__ xbB,
    const int* __restrict__ rowptr, const int* __restrict__ counts,
    const int* __restrict__ perm, ushort* __restrict__ mbA,
    ushort* __restrict__ mbB) {
    int g = blockIdx.x;
    int xcd = g & 7;
    int half = xcd >> 2;
    int sub = ((g >> 3) << 2) | (xcd & 3);       // 0..783 per half
    const ushort* xh = half ? xbB : xbA;
    ushort* mh = half ? mbB : mbA;
    int lane = threadIdx.x & 63;
    int wid = threadIdx.x >> 6;
    int n = (sub * 4 + wid) * 32 + (lane >> 1);
    int q = lane & 1;
    if (n >= N_NODES) return;
    int st = rowptr[n];
    int cn = counts[n];

    float acc[8] = {0, 0, 0, 0, 0, 0, 0, 0};
    int i = 0;
    for (; i + 4 <= cn; i += 4) {
        int p0 = perm[st + i + 0];
        int p1 = perm[st + i + 1];
        int p2 = perm[st + i + 2];
        int p3 = perm[st + i + 3];
        u16x8 v0 = *(const u16x8*)&xh[(size_t)p0 * 16 + q * 8];
        u16x8 v1 = *(const u16x8*)&xh[(size_t)p1 * 16 + q * 8];
        u16x8 v2 = *(const u16x8*)&xh[(size_t)p2 * 16 + q * 8];
        u16x8 v3 = *(const u16x8*)&xh[(size_t)p3 * 16 + q * 8];
#pragma unroll
        for (int j = 0; j < 8; ++j)
            acc[j] += (bf2f(v0[j]) + bf2f(v1[j])) + (bf2f(v2[j]) + bf2f(v3[j]));
    }
    for (; i < cn; ++i) {
        int p = perm[st + i];
        u16x8 v = *(const u16x8*)&xh[(size_t)p * 16 + q * 8];
#pragma unroll
        for (int j = 0; j < 8; ++j) acc[j] += bf2f(v[j]);
    }

    float inv = 1.0f / fmaxf((float)cn, 1.0f);
    u16x8 o;
#pragma unroll
    for (int j = 0; j < 8; ++j) o[j] = f2bf(acc[j] * inv);
    *(u16x8*)&mh[(size_t)n * 16 + q * 8] = o;
}

// ---- serial-per-lane gather-final, XCD-partitioned halves ---------------
__global__ __launch_bounds__(256) void gather_final_kernel(
    const ushort* __restrict__ tbA, const ushort* __restrict__ tbB,
    const int* __restrict__ rowptr, const int* __restrict__ counts,
    const int* __restrict__ perm, const float* __restrict__ rA,
    const float* __restrict__ rB, float* __restrict__ out) {
    int g = blockIdx.x;
    int xcd = g & 7;
    int half = xcd >> 2;
    int sub = ((g >> 3) << 2) | (xcd & 3);
    const ushort* th = half ? tbB : tbA;
    const float* rh = half ? rB : rA;
    int lane = threadIdx.x & 63;
    int wid = threadIdx.x >> 6;
    int n = (sub * 4 + wid) * 32 + (lane >> 1);
    int q = lane & 1;
    if (n >= N_NODES) return;
    int st = rowptr[n];
    int cn = counts[n];

    float acc[8] = {0, 0, 0, 0, 0, 0, 0, 0};
    int i = 0;
    for (; i + 4 <= cn; i += 4) {
        int p0 = perm[st + i + 0];
        int p1 = perm[st + i + 1];
        int p2 = perm[st + i + 2];
        int p3 = perm[st + i + 3];
        u16x8 v0 = *(const u16x8*)&th[(size_t)p0 * 16 + q * 8];
        u16x8 v1 = *(const u16x8*)&th[(size_t)p1 * 16 + q * 8];
        u16x8 v2 = *(const u16x8*)&th[(size_t)p2 * 16 + q * 8];
        u16x8 v3 = *(const u16x8*)&th[(size_t)p3 * 16 + q * 8];
#pragma unroll
        for (int j = 0; j < 8; ++j)
            acc[j] += (bf2f(v0[j]) + bf2f(v1[j])) + (bf2f(v2[j]) + bf2f(v3[j]));
    }
    for (; i < cn; ++i) {
        int p = perm[st + i];
        u16x8 v = *(const u16x8*)&th[(size_t)p * 16 + q * 8];
#pragma unroll
        for (int j = 0; j < 8; ++j) acc[j] += bf2f(v[j]);
    }

    float inv = 1.0f / fmaxf((float)cn, 1.0f);
    const float4* rp = (const float4*)&rh[(size_t)n * 16 + q * 8];
    float4 r0 = rp[0], r1 = rp[1];
    float4* op = (float4*)&out[(size_t)n * 32 + half * 16 + q * 8];
    op[0] = make_float4(acc[0] * inv + r0.x, acc[1] * inv + r0.y,
                        acc[2] * inv + r0.z, acc[3] * inv + r0.w);
    op[1] = make_float4(acc[4] * inv + r1.x, acc[5] * inv + r1.y,
                        acc[6] * inv + r1.z, acc[7] * inv + r1.w);
}

// ---- MFMA transform: weights loaded from f32 + packed in-register -------
__global__ __launch_bounds__(256) void transform_mfma_kernel(
    const ushort* __restrict__ xbA, const ushort* __restrict__ xbB,
    const ushort* __restrict__ mbA, const ushort* __restrict__ mbB,
    const float* __restrict__ W1l, const float* __restrict__ W1r,
    const float* __restrict__ W2l, const float* __restrict__ W2r,
    const float* __restrict__ b1, const float* __restrict__ b2,
    ushort* __restrict__ tbA, ushort* __restrict__ tbB,
    float* __restrict__ rA, float* __restrict__ rB) {
    __shared__ ushort hlds[4][16 * 72];
    int lane = threadIdx.x & 63;
    int wid = threadIdx.x >> 6;
    int l15 = lane & 15, lhi = lane >> 4;

    bf16x8 B1l[4], B1r[4];
#pragma unroll
    for (int jt = 0; jt < 4; ++jt) {
        B1l[jt] = pk8(&W1l[(jt * 16 + l15) * 32 + 8 * lhi]);
        B1r[jt] = pk8(&W1r[(jt * 16 + l15) * 32 + 8 * lhi]);
    }
    bf16x8 B2l[2][2], B2r[2][2];
#pragma unroll
    for (int ct = 0; ct < 2; ++ct)
#pragma unroll
        for (int kc = 0; kc < 2; ++kc) {
            B2l[ct][kc] = pk8(&W2l[(ct * 16 + l15) * 64 + kc * 32 + 8 * lhi]);
            B2r[ct][kc] = pk8(&W2r[(ct * 16 + l15) * 64 + kc * 32 + 8 * lhi]);
        }
    float bias1[4];
#pragma unroll
    for (int jt = 0; jt < 4; ++jt) bias1[jt] = b1[jt * 16 + l15];
    float bias2[2] = { b2[l15], b2[16 + l15] };

    ushort* hl = hlds[wid];

#pragma unroll
    for (int chunk = 0; chunk < 2; ++chunk) {
        int n0 = blockIdx.x * 128 + wid * 32 + chunk * 16;
        int nrow = n0 + l15;
        bf16x8 Am = {}, Ax = {};
        if (nrow < N_NODES) {
            const ushort* ms = (lhi < 2) ? mbA : mbB;
            const ushort* xs = (lhi < 2) ? xbA : xbB;
            Am = *(const bf16x8*)&ms[(size_t)nrow * 16 + 8 * (lhi & 1)];
            Ax = *(const bf16x8*)&xs[(size_t)nrow * 16 + 8 * (lhi & 1)];
        }
#pragma unroll
        for (int jt = 0; jt < 4; ++jt) {
            f32x4 acc = {};
            acc = __builtin_amdgcn_mfma_f32_16x16x32_bf16(Am, B1l[jt], acc, 0, 0, 0);
            acc = __builtin_amdgcn_mfma_f32_16x16x32_bf16(Ax, B1r[jt], acc, 0, 0, 0);
#pragma unroll
            for (int reg = 0; reg < 4; ++reg) {
                float h = fmaxf(acc[reg] + bias1[jt], 0.0f);
                hl[(lhi * 4 + reg) * 72 + jt * 16 + l15] = f2bf(h);
            }
        }
        bf16x8 Ah0 = *(const bf16x8*)&hl[l15 * 72 + 8 * lhi];
        bf16x8 Ah1 = *(const bf16x8*)&hl[l15 * 72 + 32 + 8 * lhi];
#pragma unroll
        for (int ct = 0; ct < 2; ++ct) {
            f32x4 acc = {};
            acc = __builtin_amdgcn_mfma_f32_16x16x32_bf16(Ah0, B2l[ct][0], acc, 0, 0, 0);
            acc = __builtin_amdgcn_mfma_f32_16x16x32_bf16(Ah1, B2l[ct][1], acc, 0, 0, 0);
            ushort* tdst = ct ? tbB : tbA;
#pragma unroll
            for (int reg = 0; reg < 4; ++reg) {
                int nr = n0 + lhi * 4 + reg;
                if (nr < N_NODES)
                    tdst[(size_t)nr * 16 + l15] = f2bf(acc[reg]);
            }
        }
#pragma unroll
        for (int ct = 0; ct < 2; ++ct) {
            f32x4 acc = {};
            acc = __builtin_amdgcn_mfma_f32_16x16x32_bf16(Ah0, B2r[ct][0], acc, 0, 0, 0);
            acc = __builtin_amdgcn_mfma_f32_16x16x32_bf16(Ah1, B2r[ct][1], acc, 0, 0, 0);
            float* rdst = ct ? rB : rA;
#pragma unroll
            for (int reg = 0; reg < 4; ++reg) {
                int nr = n0 + lhi * 4 + reg;
                if (nr < N_NODES)
                    rdst[(size_t)nr * 16 + l15] = acc[reg] + bias2[ct];
            }
        }
    }
}

// ---- launch -------------------------------------------------------------

extern "C" void kernel_launch(void* const* d_in, const int* in_sizes, int n_in,
                              void* d_out, int out_size, void* d_ws, size_t ws_size,
                              hipStream_t stream) {
    const float* x   = (const float*)d_in[0];
    const float* W1l = (const float*)d_in[1];
    const float* W1r = (const float*)d_in[2];
    const float* b1  = (const float*)d_in[3];
    const float* W2l = (const float*)d_in[4];
    const float* W2r = (const float*)d_in[5];
    const float* b2  = (const float*)d_in[6];
    const int*   ei  = (const int*)d_in[7];   // [2, N_EDGES]
    const int* src = ei;
    const int* dst = ei + N_EDGES;

    char* ws = (char*)d_ws;
    int*      bcnt   = (int*)ws;             ws += (size_t)(NB + 8) * 4;
    int*      counts = (int*)ws;             ws += (size_t)N_NODES * 4;
    int*      rowptr = (int*)ws;             ws += (size_t)N_NODES * 4;
    int*      perm   = (int*)ws;             ws += (size_t)NB * REG * 4;   // 7.2 MB
    unsigned* tmp    = (unsigned*)ws;        ws += (size_t)NB * REG * 4;   // 7.2 MB
    // mbA/mbB (3.2MB each) alias tmp (7.2MB): tmp dead after count_place.
    ushort*   mbA    = (ushort*)tmp;
    ushort*   mbB    = mbA + (size_t)N_NODES * 16;
    ushort*   xbA    = (ushort*)ws;          ws += (size_t)N_NODES * 16 * 2;
    ushort*   xbB    = (ushort*)ws;          ws += (size_t)N_NODES * 16 * 2;
    ushort*   tbA    = (ushort*)ws;          ws += (size_t)N_NODES * 16 * 2;
    ushort*   tbB    = (ushort*)ws;          ws += (size_t)N_NODES * 16 * 2;
    float*    rA     = (float*)ws;           ws += (size_t)N_NODES * 16 * 4;
    float*    rB     = (float*)ws;           ws += (size_t)N_NODES * 16 * 4;

    dim3 blk(256);

    hipMemsetAsync(bcnt, 0, (size_t)(NB + 8) * 4, stream);
    place_kernel<<<NBLK, blk, 0, stream>>>(src, dst, x, xbA, xbB, bcnt, tmp);
    count_place_kernel<<<NB, dim3(512), 0, stream>>>(tmp, bcnt, counts, rowptr, perm);

    gather_mean_kernel<<<2 * GSG8, blk, 0, stream>>>(xbA, xbB, rowptr, counts,
                                                     perm, mbA, mbB);
    transform_mfma_kernel<<<(N_NODES + 127) / 128, blk, 0, stream>>>(
        xbA, xbB, mbA, mbB, W1l, W1r, W2l, W2r, b1, b2, tbA, tbB, rA, rB);
    gather_final_kernel<<<2 * GSG8, blk, 0, stream>>>(tbA, tbB, rowptr, counts,
                                                      perm, rA, rB, (float*)d_out);
}

// Round 20
// 123.430 us; speedup vs baseline: 1.1697x; 1.1059x over previous
//
#include <hip/hip_runtime.h>

#define N_NODES 100000
#define N_EDGES 1600000
#define IN_C 32
#define HID_C 64
#define OUT_C 32

#define EPB 4096                                 // edges per place block
#define NBLK ((N_EDGES + EPB - 1) / EPB)         // 391
#define BSH 8                                    // 256 nodes per bucket
#define BKN (1 << BSH)
#define NB ((N_NODES + BKN - 1) / BKN)           // 391
#define REG 4608                                 // fixed slots per bucket

typedef __attribute__((ext_vector_type(8))) short bf16x8;
typedef __attribute__((ext_vector_type(8))) unsigned short u16x8;
typedef __attribute__((ext_vector_type(4))) float f32x4;

__device__ __forceinline__ unsigned short f2bf(float f) {
    unsigned u = __float_as_uint(f);
    return (unsigned short)((u + 0x7fffu + ((u >> 16) & 1u)) >> 16);
}
__device__ __forceinline__ float bf2f(unsigned short h) {
    return __uint_as_float((unsigned)h << 16);
}

// ---- weights cast + zero bucket counters --------------------------------
__global__ void cast_w_kernel(const float* __restrict__ w1l,
                              const float* __restrict__ w1r,
                              const float* __restrict__ w2l,
                              const float* __restrict__ w2r,
                              ushort* __restrict__ wb, int* __restrict__ bcnt) {
    for (int i = threadIdx.x; i < NB; i += 256) bcnt[i] = 0;
    for (int i = threadIdx.x; i < 8192; i += 256) {
        float v;
        if (i < 2048) v = w1l[i];
        else if (i < 4096) v = w1r[i - 2048];
        else if (i < 6144) v = w2l[i - 4096];
        else v = w2r[i - 6144];
        wb[i] = f2bf(v);
    }
}

// ---- place: LDS hist -> global range reservation -> write packed pairs --
__global__ __launch_bounds__(256) void place_kernel(
    const int* __restrict__ src, const int* __restrict__ dst,
    const float* __restrict__ x, ushort* __restrict__ xbA,
    ushort* __restrict__ xbB, int* __restrict__ bcnt,
    unsigned* __restrict__ tmp) {
    for (int ci = blockIdx.x * 256 + threadIdx.x; ci < N_NODES * IN_C / 8;
         ci += NBLK * 256) {
        int n = ci >> 2;
        int oc = ci & 3;
        const float4* p = (const float4*)&x[(size_t)ci * 8];
        float4 a = p[0], b = p[1];
        u16x8 o;
        o[0] = f2bf(a.x); o[1] = f2bf(a.y); o[2] = f2bf(a.z); o[3] = f2bf(a.w);
        o[4] = f2bf(b.x); o[5] = f2bf(b.y); o[6] = f2bf(b.z); o[7] = f2bf(b.w);
        ushort* dstp = (oc < 2) ? xbA : xbB;
        *(u16x8*)&dstp[(size_t)n * 16 + (oc & 1) * 8] = o;
    }

    __shared__ int lh[NB];
    __shared__ int cur[NB];
    for (int i = threadIdx.x; i < NB; i += 256) lh[i] = 0;
    __syncthreads();

    int base = blockIdx.x * EPB;
    int se[16], de[16];
#pragma unroll
    for (int j = 0; j < 16; ++j) {
        int e = base + j * 256 + threadIdx.x;
        bool v = e < N_EDGES;
        se[j] = v ? src[e] : -1;
        de[j] = v ? dst[e] : 0;
        if (v) atomicAdd(&lh[de[j] >> BSH], 1);
    }
    __syncthreads();
    for (int i = threadIdx.x; i < NB; i += 256)
        cur[i] = i * REG + atomicAdd(&bcnt[i], lh[i]);
    __syncthreads();
#pragma unroll
    for (int j = 0; j < 16; ++j) {
        if (se[j] >= 0) {
            int slot = atomicAdd(&cur[de[j] >> BSH], 1);
            tmp[slot] = ((unsigned)se[j] << 8) | (unsigned)(de[j] & (BKN - 1));
        }
    }
}

// ---- count_place: per-bucket counts + rowptr + perm (one tmp read) ------
__global__ __launch_bounds__(512) void count_place_kernel(
    const unsigned* __restrict__ tmp, const int* __restrict__ bcnt,
    int* __restrict__ counts, int* __restrict__ rowptr,
    int* __restrict__ perm) {
    __shared__ int lcnt[BKN];
    __shared__ int sscan[BKN];
    __shared__ int cur[BKN];
    int b = blockIdx.x;
    int tid = threadIdx.x;
    int start = b * REG;
    int end = start + bcnt[b];

    unsigned pv[9];
    int npv = 0;
    for (int i = start + tid; i < end; i += 512) pv[npv++] = tmp[i];

    if (tid < BKN) lcnt[tid] = 0;
    __syncthreads();
    for (int k = 0; k < npv; ++k)
        atomicAdd(&lcnt[pv[k] & (BKN - 1)], 1);
    __syncthreads();
    if (tid < BKN) sscan[tid] = lcnt[tid];
    __syncthreads();
    for (int o = 1; o < BKN; o <<= 1) {
        int v = 0;
        if (tid < BKN && tid >= o) v = sscan[tid - o];
        __syncthreads();
        if (tid < BKN) sscan[tid] += v;
        __syncthreads();
    }
    if (tid < BKN) {
        int excl = sscan[tid] - lcnt[tid] + start;
        cur[tid] = excl;
        int n = (b << BSH) + tid;
        if (n < N_NODES) { rowptr[n] = excl; counts[n] = lcnt[tid]; }
    }
    __syncthreads();
    for (int k = 0; k < npv; ++k) {
        int slot = atomicAdd(&cur[pv[k] & (BKN - 1)], 1);
        perm[slot] = (int)(pv[k] >> 8);
    }
}

// 784 blocks per half, 128 nodes/block; grid = 1568 (multiple of 8).
// XCD partition: blockIdx%8 in {0..3} -> half A, {4..7} -> half B, so each
// XCD's 4MB L2 holds ONE 3.2MB half-table while both halves run at full TLP.
#define GSG8 784

// ---- serial-per-lane gather-mean, XCD-partitioned halves ----------------
// 8-edge chunks (was 4): fewer loop branches, 8x16B feature loads in flight.
__global__ __launch_bounds__(256) void gather_mean_kernel(
    const ushort* __restrict__ xbA, const ushort* __restrict__ xbB,
    const int* __restrict__ rowptr, const int* __restrict__ counts,
    const int* __restrict__ perm, ushort* __restrict__ mbA,
    ushort* __restrict__ mbB) {
    int g = blockIdx.x;
    int xcd = g & 7;
    int half = xcd >> 2;
    int sub = ((g >> 3) << 2) | (xcd & 3);       // 0..783 per half
    const ushort* xh = half ? xbB : xbA;
    ushort* mh = half ? mbB : mbA;
    int lane = threadIdx.x & 63;
    int wid = threadIdx.x >> 6;
    int n = (sub * 4 + wid) * 32 + (lane >> 1);
    int q = lane & 1;
    if (n >= N_NODES) return;
    int st = rowptr[n];
    int cn = counts[n];

    float acc[8] = {0, 0, 0, 0, 0, 0, 0, 0};
    int i = 0;
    for (; i + 8 <= cn; i += 8) {
        int pp[8];
#pragma unroll
        for (int e = 0; e < 8; ++e) pp[e] = perm[st + i + e];
        u16x8 vv[8];
#pragma unroll
        for (int e = 0; e < 8; ++e)
            vv[e] = *(const u16x8*)&xh[(size_t)pp[e] * 16 + q * 8];
#pragma unroll
        for (int j = 0; j < 8; ++j)
            acc[j] += ((bf2f(vv[0][j]) + bf2f(vv[1][j])) +
                       (bf2f(vv[2][j]) + bf2f(vv[3][j]))) +
                      ((bf2f(vv[4][j]) + bf2f(vv[5][j])) +
                       (bf2f(vv[6][j]) + bf2f(vv[7][j])));
    }
    for (; i + 4 <= cn; i += 4) {
        int p0 = perm[st + i + 0];
        int p1 = perm[st + i + 1];
        int p2 = perm[st + i + 2];
        int p3 = perm[st + i + 3];
        u16x8 v0 = *(const u16x8*)&xh[(size_t)p0 * 16 + q * 8];
        u16x8 v1 = *(const u16x8*)&xh[(size_t)p1 * 16 + q * 8];
        u16x8 v2 = *(const u16x8*)&xh[(size_t)p2 * 16 + q * 8];
        u16x8 v3 = *(const u16x8*)&xh[(size_t)p3 * 16 + q * 8];
#pragma unroll
        for (int j = 0; j < 8; ++j)
            acc[j] += (bf2f(v0[j]) + bf2f(v1[j])) + (bf2f(v2[j]) + bf2f(v3[j]));
    }
    for (; i < cn; ++i) {
        int p = perm[st + i];
        u16x8 v = *(const u16x8*)&xh[(size_t)p * 16 + q * 8];
#pragma unroll
        for (int j = 0; j < 8; ++j) acc[j] += bf2f(v[j]);
    }

    float inv = 1.0f / fmaxf((float)cn, 1.0f);
    u16x8 o;
#pragma unroll
    for (int j = 0; j < 8; ++j) o[j] = f2bf(acc[j] * inv);
    *(u16x8*)&mh[(size_t)n * 16 + q * 8] = o;
}

// ---- serial-per-lane gather-final, XCD-partitioned halves ---------------
__global__ __launch_bounds__(256) void gather_final_kernel(
    const ushort* __restrict__ tbA, const ushort* __restrict__ tbB,
    const int* __restrict__ rowptr, const int* __restrict__ counts,
    const int* __restrict__ perm, const float* __restrict__ rA,
    const float* __restrict__ rB, float* __restrict__ out) {
    int g = blockIdx.x;
    int xcd = g & 7;
    int half = xcd >> 2;
    int sub = ((g >> 3) << 2) | (xcd & 3);
    const ushort* th = half ? tbB : tbA;
    const float* rh = half ? rB : rA;
    int lane = threadIdx.x & 63;
    int wid = threadIdx.x >> 6;
    int n = (sub * 4 + wid) * 32 + (lane >> 1);
    int q = lane & 1;
    if (n >= N_NODES) return;
    int st = rowptr[n];
    int cn = counts[n];

    float acc[8] = {0, 0, 0, 0, 0, 0, 0, 0};
    int i = 0;
    for (; i + 8 <= cn; i += 8) {
        int pp[8];
#pragma unroll
        for (int e = 0; e < 8; ++e) pp[e] = perm[st + i + e];
        u16x8 vv[8];
#pragma unroll
        for (int e = 0; e < 8; ++e)
            vv[e] = *(const u16x8*)&th[(size_t)pp[e] * 16 + q * 8];
#pragma unroll
        for (int j = 0; j < 8; ++j)
            acc[j] += ((bf2f(vv[0][j]) + bf2f(vv[1][j])) +
                       (bf2f(vv[2][j]) + bf2f(vv[3][j]))) +
                      ((bf2f(vv[4][j]) + bf2f(vv[5][j])) +
                       (bf2f(vv[6][j]) + bf2f(vv[7][j])));
    }
    for (; i + 4 <= cn; i += 4) {
        int p0 = perm[st + i + 0];
        int p1 = perm[st + i + 1];
        int p2 = perm[st + i + 2];
        int p3 = perm[st + i + 3];
        u16x8 v0 = *(const u16x8*)&th[(size_t)p0 * 16 + q * 8];
        u16x8 v1 = *(const u16x8*)&th[(size_t)p1 * 16 + q * 8];
        u16x8 v2 = *(const u16x8*)&th[(size_t)p2 * 16 + q * 8];
        u16x8 v3 = *(const u16x8*)&th[(size_t)p3 * 16 + q * 8];
#pragma unroll
        for (int j = 0; j < 8; ++j)
            acc[j] += (bf2f(v0[j]) + bf2f(v1[j])) + (bf2f(v2[j]) + bf2f(v3[j]));
    }
    for (; i < cn; ++i) {
        int p = perm[st + i];
        u16x8 v = *(const u16x8*)&th[(size_t)p * 16 + q * 8];
#pragma unroll
        for (int j = 0; j < 8; ++j) acc[j] += bf2f(v[j]);
    }

    float inv = 1.0f / fmaxf((float)cn, 1.0f);
    const float4* rp = (const float4*)&rh[(size_t)n * 16 + q * 8];
    float4 r0 = rp[0], r1 = rp[1];
    float4* op = (float4*)&out[(size_t)n * 32 + half * 16 + q * 8];
    op[0] = make_float4(acc[0] * inv + r0.x, acc[1] * inv + r0.y,
                        acc[2] * inv + r0.z, acc[3] * inv + r0.w);
    op[1] = make_float4(acc[4] * inv + r1.x, acc[5] * inv + r1.y,
                        acc[6] * inv + r1.z, acc[7] * inv + r1.w);
}

// ---- MFMA transform: reads/writes split half-tables ---------------------
__global__ __launch_bounds__(256) void transform_mfma_kernel(
    const ushort* __restrict__ xbA, const ushort* __restrict__ xbB,
    const ushort* __restrict__ mbA, const ushort* __restrict__ mbB,
    const ushort* __restrict__ wb, const float* __restrict__ b1,
    const float* __restrict__ b2, ushort* __restrict__ tbA,
    ushort* __restrict__ tbB, float* __restrict__ rA,
    float* __restrict__ rB) {
    __shared__ ushort hlds[4][16 * 72];
    int lane = threadIdx.x & 63;
    int wid = threadIdx.x >> 6;
    int l15 = lane & 15, lhi = lane >> 4;

    const ushort* w1l = wb;
    const ushort* w1r = wb + 2048;
    const ushort* w2l = wb + 4096;
    const ushort* w2r = wb + 6144;

    bf16x8 B1l[4], B1r[4];
#pragma unroll
    for (int jt = 0; jt < 4; ++jt) {
        B1l[jt] = *(const bf16x8*)&w1l[(jt * 16 + l15) * 32 + 8 * lhi];
        B1r[jt] = *(const bf16x8*)&w1r[(jt * 16 + l15) * 32 + 8 * lhi];
    }
    bf16x8 B2l[2][2], B2r[2][2];
#pragma unroll
    for (int ct = 0; ct < 2; ++ct)
#pragma unroll
        for (int kc = 0; kc < 2; ++kc) {
            B2l[ct][kc] = *(const bf16x8*)&w2l[(ct * 16 + l15) * 64 + kc * 32 + 8 * lhi];
            B2r[ct][kc] = *(const bf16x8*)&w2r[(ct * 16 + l15) * 64 + kc * 32 + 8 * lhi];
        }
    float bias1[4];
#pragma unroll
    for (int jt = 0; jt < 4; ++jt) bias1[jt] = b1[jt * 16 + l15];
    float bias2[2] = { b2[l15], b2[16 + l15] };

    ushort* hl = hlds[wid];

#pragma unroll
    for (int chunk = 0; chunk < 2; ++chunk) {
        int n0 = blockIdx.x * 128 + wid * 32 + chunk * 16;
        int nrow = n0 + l15;
        bf16x8 Am = {}, Ax = {};
        if (nrow < N_NODES) {
            const ushort* ms = (lhi < 2) ? mbA : mbB;
            const ushort* xs = (lhi < 2) ? xbA : xbB;
            Am = *(const bf16x8*)&ms[(size_t)nrow * 16 + 8 * (lhi & 1)];
            Ax = *(const bf16x8*)&xs[(size_t)nrow * 16 + 8 * (lhi & 1)];
        }
#pragma unroll
        for (int jt = 0; jt < 4; ++jt) {
            f32x4 acc = {};
            acc = __builtin_amdgcn_mfma_f32_16x16x32_bf16(Am, B1l[jt], acc, 0, 0, 0);
            acc = __builtin_amdgcn_mfma_f32_16x16x32_bf16(Ax, B1r[jt], acc, 0, 0, 0);
#pragma unroll
            for (int reg = 0; reg < 4; ++reg) {
                float h = fmaxf(acc[reg] + bias1[jt], 0.0f);
                hl[(lhi * 4 + reg) * 72 + jt * 16 + l15] = f2bf(h);
            }
        }
        bf16x8 Ah0 = *(const bf16x8*)&hl[l15 * 72 + 8 * lhi];
        bf16x8 Ah1 = *(const bf16x8*)&hl[l15 * 72 + 32 + 8 * lhi];
#pragma unroll
        for (int ct = 0; ct < 2; ++ct) {
            f32x4 acc = {};
            acc = __builtin_amdgcn_mfma_f32_16x16x32_bf16(Ah0, B2l[ct][0], acc, 0, 0, 0);
            acc = __builtin_amdgcn_mfma_f32_16x16x32_bf16(Ah1, B2l[ct][1], acc, 0, 0, 0);
            ushort* tdst = ct ? tbB : tbA;
#pragma unroll
            for (int reg = 0; reg < 4; ++reg) {
                int nr = n0 + lhi * 4 + reg;
                if (nr < N_NODES)
                    tdst[(size_t)nr * 16 + l15] = f2bf(acc[reg]);
            }
        }
#pragma unroll
        for (int ct = 0; ct < 2; ++ct) {
            f32x4 acc = {};
            acc = __builtin_amdgcn_mfma_f32_16x16x32_bf16(Ah0, B2r[ct][0], acc, 0, 0, 0);
            acc = __builtin_amdgcn_mfma_f32_16x16x32_bf16(Ah1, B2r[ct][1], acc, 0, 0, 0);
            float* rdst = ct ? rB : rA;
#pragma unroll
            for (int reg = 0; reg < 4; ++reg) {
                int nr = n0 + lhi * 4 + reg;
                if (nr < N_NODES)
                    rdst[(size_t)nr * 16 + l15] = acc[reg] + bias2[ct];
            }
        }
    }
}

// ---- launch -------------------------------------------------------------

extern "C" void kernel_launch(void* const* d_in, const int* in_sizes, int n_in,
                              void* d_out, int out_size, void* d_ws, size_t ws_size,
                              hipStream_t stream) {
    const float* x   = (const float*)d_in[0];
    const float* W1l = (const float*)d_in[1];
    const float* W1r = (const float*)d_in[2];
    const float* b1  = (const float*)d_in[3];
    const float* W2l = (const float*)d_in[4];
    const float* W2r = (const float*)d_in[5];
    const float* b2  = (const float*)d_in[6];
    const int*   ei  = (const int*)d_in[7];   // [2, N_EDGES]
    const int* src = ei;
    const int* dst = ei + N_EDGES;

    char* ws = (char*)d_ws;
    int*      bcnt   = (int*)ws;             ws += (size_t)(NB + 8) * 4;
    int*      counts = (int*)ws;             ws += (size_t)N_NODES * 4;
    int*      rowptr = (int*)ws;             ws += (size_t)N_NODES * 4;
    int*      perm   = (int*)ws;             ws += (size_t)NB * REG * 4;   // 7.2 MB
    unsigned* tmp    = (unsigned*)ws;        ws += (size_t)NB * REG * 4;   // 7.2 MB
    // mbA/mbB (3.2MB each) alias tmp (7.2MB): tmp dead after count_place.
    ushort*   mbA    = (ushort*)tmp;
    ushort*   mbB    = mbA + (size_t)N_NODES * 16;
    ushort*   xbA    = (ushort*)ws;          ws += (size_t)N_NODES * 16 * 2;
    ushort*   xbB    = (ushort*)ws;          ws += (size_t)N_NODES * 16 * 2;
    ushort*   wb     = (ushort*)ws;          ws += (size_t)8192 * 2;
    ushort*   tbA    = (ushort*)ws;          ws += (size_t)N_NODES * 16 * 2;
    ushort*   tbB    = (ushort*)ws;          ws += (size_t)N_NODES * 16 * 2;
    float*    rA     = (float*)ws;           ws += (size_t)N_NODES * 16 * 4;
    float*    rB     = (float*)ws;           ws += (size_t)N_NODES * 16 * 4;

    dim3 blk(256);

    cast_w_kernel<<<1, blk, 0, stream>>>(W1l, W1r, W2l, W2r, wb, bcnt);
    place_kernel<<<NBLK, blk, 0, stream>>>(src, dst, x, xbA, xbB, bcnt, tmp);
    count_place_kernel<<<NB, dim3(512), 0, stream>>>(tmp, bcnt, counts, rowptr, perm);

    gather_mean_kernel<<<2 * GSG8, blk, 0, stream>>>(xbA, xbB, rowptr, counts,
                                                     perm, mbA, mbB);
    transform_mfma_kernel<<<(N_NODES + 127) / 128, blk, 0, stream>>>(
        xbA, xbB, mbA, mbB, wb, b1, b2, tbA, tbB, rA, rB);
    gather_final_kernel<<<2 * GSG8, blk, 0, stream>>>(tbA, tbB, rowptr, counts,
                                                      perm, rA, rB, (float*)d_out);
}